// Round 9
// baseline (427.734 us; speedup 1.0000x reference)
//
#include <hip/hip_runtime.h>
#include <cstddef>
#include <cstdint>

#define NE 2048
#define NX 3
#define NROWS (NE - 1)               // rows solved by back-substitution: i = 0..2046
#define BS 64                        // block size (rows per block)
#define BR (3 * BS)                  // 192
#define NBLK 32
#define NPAIR 16
#define NCH 8                        // K-staging chunks in k_tinv
#define CHS 8                        // steps per chunk (NCH*CHS == BS)
#define CHQ (CHS * 9 * BS)           // 4608 floats per chunk
#define TTH 512                      // k_tinv threads
#define PERTH (CHQ / TTH)            // 9 floats per thread

// ws layout (floats):
//   wf  [3*NE]        @ 0          wf[p][j] = w_j * F[p][j]
//   acc [3*NE]        @ 3*NE       running RHS accumulator
//   G   [NBLK*BR*BR]  @ 6*NE       per-block T^{-1}, ROW-major: G[b][row][col]
//   cnt [ints]        @ end        per-pair ticket counters (zeroed by k_init)

static __device__ __forceinline__ float dy_of(const float* E) {
    return logf(E[NE - 1] / E[0]) / (float)(NE - 1);
}

__global__ void k_init(const float* __restrict__ E, const float* __restrict__ R,
                       const float* __restrict__ K, const float* __restrict__ S0,
                       const float* __restrict__ SC,
                       float* __restrict__ out, float* __restrict__ wf,
                       float* __restrict__ acc, int* __restrict__ cnt) {
    int i = blockIdx.x * blockDim.x + threadIdx.x;
    if (blockIdx.x == 0 && threadIdx.x < NBLK) cnt[threadIdx.x] = 0;
    if (i >= NE) return;
    const size_t PL = (size_t)NE * NE;
    float dy = dy_of(E);
    float wlast = 0.5f * dy * E[NE - 1];
    float srcl[NX], Fl[NX];
#pragma unroll
    for (int p = 0; p < NX; ++p) srcl[p] = S0[p] / R[p * NE + NE - 1];
#pragma unroll
    for (int x = 0; x < NX; ++x) {
        float s = SC[x * NE + NE - 1];
#pragma unroll
        for (int p = 0; p < NX; ++p)
            s += K[(size_t)(x * NX + p) * PL + (size_t)(NE - 1) * NE + (NE - 1)] * srcl[p];
        Fl[x] = s / R[x * NE + NE - 1];
    }
    out[i] = E[i];  // output row 0 = E_grid
    if (i == NE - 1) {
#pragma unroll
        for (int x = 0; x < NX; ++x) {
            out[(1 + x) * NE + i] = Fl[x] > 0.f ? Fl[x] : 0.f;
            wf[x * NE + i] = wlast * Fl[x];
            acc[x * NE + i] = 0.f;
        }
        return;
    }
#pragma unroll
    for (int x = 0; x < NX; ++x) {
        float s = SC[x * NE + i];
#pragma unroll
        for (int p = 0; p < NX; ++p)
            s += K[(size_t)(x * NX + p) * PL + (size_t)i * NE + (NE - 1)] *
                 (wlast * Fl[p] + srcl[p]);
        acc[x * NE + i] = s;
    }
}

// Per-block inverse. grid (NBLK, 3), 512 threads: 64 columns/WG, 8 threads/col.
__global__ __launch_bounds__(TTH) void k_tinv(const float* __restrict__ E,
                                              const float* __restrict__ R,
                                              const float* __restrict__ K,
                                              float* __restrict__ G) {
    __shared__ float4 Xs4[BS][BS + 1];  // 66560 B: [jj][cloc] = (x0,x1,x2,_)
    __shared__ float Kst[CHS][BS][12];  // 24576 B: w-folded K rows, slot 4r+p
    __shared__ float Binv[BS][9];
    __shared__ float wloc[BS];
    const size_t PL = (size_t)NE * NE;
    int b = blockIdx.x;
    int g = blockIdx.y;                 // column group 0..2
    int i0 = b * BS;
    int tid = threadIdx.x;
    float dy = dy_of(E);

    if (tid < BS) {
        int j = i0 + tid;
        wloc[tid] = (j < NE - 1) ? dy * E[j] : 0.f;
        int ii = tid, i = i0 + ii;
        float b00, b01, b02, b10, b11, b12, b20, b21, b22;
        if (i < NROWS) {
            float h = -0.5f * dy * E[i];
            size_t d = (size_t)i * NE + i;
            b00 = h * K[0 * PL + d] + R[0 * NE + i];
            b01 = h * K[1 * PL + d];
            b02 = h * K[2 * PL + d];
            b10 = h * K[3 * PL + d];
            b11 = h * K[4 * PL + d] + R[1 * NE + i];
            b12 = h * K[5 * PL + d];
            b20 = h * K[6 * PL + d];
            b21 = h * K[7 * PL + d];
            b22 = h * K[8 * PL + d] + R[2 * NE + i];
        } else {
            b00 = 1.f; b01 = 0.f; b02 = 0.f;
            b10 = 0.f; b11 = 1.f; b12 = 0.f;
            b20 = 0.f; b21 = 0.f; b22 = 1.f;
        }
        float C00 = b11 * b22 - b12 * b21;
        float C01 = -(b10 * b22 - b12 * b20);
        float C02 = b10 * b21 - b11 * b20;
        float C10 = -(b01 * b22 - b02 * b21);
        float C11 = b00 * b22 - b02 * b20;
        float C12 = -(b00 * b21 - b01 * b20);
        float C20 = b01 * b12 - b02 * b11;
        float C21 = -(b00 * b12 - b02 * b10);
        float C22 = b00 * b11 - b01 * b10;
        float inv = 1.f / (b00 * C00 + b01 * C01 + b02 * C02);
        Binv[ii][0] = C00 * inv; Binv[ii][1] = C10 * inv; Binv[ii][2] = C20 * inv;
        Binv[ii][3] = C01 * inv; Binv[ii][4] = C11 * inv; Binv[ii][5] = C21 * inv;
        Binv[ii][6] = C02 * inv; Binv[ii][7] = C12 * inv; Binv[ii][8] = C22 * inv;
    }
    __syncthreads();

    float rg[PERTH];
#pragma unroll
    for (int k = 0; k < PERTH; ++k) {
        int q = tid + k * TTH;
        int s = q / (9 * BS);
        int pair = (q / BS) % 9;
        int jj = q & (BS - 1);
        int row = i0 + (BS - 1) - s;
        rg[k] = K[(size_t)pair * PL + (size_t)row * NE + (i0 + jj)];
    }

    int cloc = tid >> 3, sub = tid & 7;
    int colb = g * BS + cloc;

    for (int c = 0; c < NCH; ++c) {
        if (c > 0) __syncthreads();
#pragma unroll
        for (int k = 0; k < PERTH; ++k) {
            int q = tid + k * TTH;
            int s = q / (9 * BS);
            int pair = (q / BS) % 9;
            int jj = q & (BS - 1);
            Kst[s][jj][4 * (pair / 3) + (pair % 3)] = rg[k] * wloc[jj];
        }
        __syncthreads();
        if (c + 1 < NCH) {
#pragma unroll
            for (int k = 0; k < PERTH; ++k) {
                int q = tid + k * TTH;
                int s = q / (9 * BS);
                int pair = (q / BS) % 9;
                int jj = q & (BS - 1);
                int row = i0 + (BS - 1) - ((c + 1) * CHS + s);
                rg[k] = K[(size_t)pair * PL + (size_t)row * NE + (i0 + jj)];
            }
        }
        for (int s = 0; s < CHS; ++s) {
            int ii = (BS - 1) - (c * CHS + s);
            int i = i0 + ii;
            float v0 = 0.f, v1 = 0.f, v2 = 0.f;
            if (sub == 0) {
                v0 = (colb == 3 * ii + 0) ? 1.f : 0.f;
                v1 = (colb == 3 * ii + 1) ? 1.f : 0.f;
                v2 = (colb == 3 * ii + 2) ? 1.f : 0.f;
            }
            if (i < NROWS) {
                for (int jj = ii + 1 + sub; jj < BS; jj += 8) {
                    const float* kp = &Kst[s][jj][0];
                    float4 k0 = *(const float4*)(kp);
                    float4 k1 = *(const float4*)(kp + 4);
                    float4 k2 = *(const float4*)(kp + 8);
                    float4 xv = Xs4[jj][cloc];
                    v0 += k0.x * xv.x + k0.y * xv.y + k0.z * xv.z;
                    v1 += k1.x * xv.x + k1.y * xv.y + k1.z * xv.z;
                    v2 += k2.x * xv.x + k2.y * xv.y + k2.z * xv.z;
                }
            }
            v0 += __shfl_xor(v0, 1); v0 += __shfl_xor(v0, 2); v0 += __shfl_xor(v0, 4);
            v1 += __shfl_xor(v1, 1); v1 += __shfl_xor(v1, 2); v1 += __shfl_xor(v1, 4);
            v2 += __shfl_xor(v2, 1); v2 += __shfl_xor(v2, 2); v2 += __shfl_xor(v2, 4);
            if (sub == 0) {
                float f0, f1, f2;
                if (i < NROWS) {
                    const float* bv = Binv[ii];
                    f0 = bv[0] * v0 + bv[1] * v1 + bv[2] * v2;
                    f1 = bv[3] * v0 + bv[4] * v1 + bv[5] * v2;
                    f2 = bv[6] * v0 + bv[7] * v1 + bv[8] * v2;
                } else {
                    f0 = v0; f1 = v1; f2 = v2;  // identity row (pad)
                }
                Xs4[ii][cloc] = make_float4(f0, f1, f2, 0.f);
            }
            __builtin_amdgcn_wave_barrier();  // order LDS write->read across steps
        }
    }
    __syncthreads();
    // bulk Gt dump, ROW-major: G[b][r][g*64+cl]
    float* Gb = G + (size_t)b * BR * BR;
    for (int t = tid; t < BS * BR; t += TTH) {
        int r = t / BS, cl = t % BS;
        Gb[(size_t)r * BR + g * BS + cl] = ((const float*)&Xs4[r / 3][cl])[r % 3];
    }
}

// Pair-merged stage S(m), blocks A=2m, C=2m+1:
//   far WGs: cols of blocks 2m+2,2m+3 x all rows < (2m+2)*64 -> acc
//   full-grid relaxed ticket; winner WG:
//     F_C = G[C] @ a_C;  z = Dnear @ F_C (direct K reads, w folded);
//     F_A = G[A] @ (a_A + z);  writes out/wf for both blocks.
__global__ __launch_bounds__(512) void k_pair(const float* __restrict__ E,
                                              const float* __restrict__ K,
                                              const float* __restrict__ G,
                                              float* __restrict__ acc,
                                              float* __restrict__ wf,
                                              float* __restrict__ out,
                                              int* __restrict__ cnt,
                                              int m, int nFar) {
    const size_t PL = (size_t)NE * NE;
    int A = 2 * m, C = 2 * m + 1;
    int iA0 = A * BS, jC0 = C * BS;
    int tid = threadIdx.x;
    int bid = blockIdx.x;
    int lane = tid & 63, wv = tid >> 6;
    __shared__ int win;

    if (bid < nFar) {
        // far: 8 rows per WG (one per wave), 128 cols (blocks 2m+2, 2m+3)
        int jbase = (2 * m + 2) * BS;
        int row = bid * 8 + wv;
        int j1 = jbase + lane, j2 = j1 + BS;
        float w10 = wf[0 * NE + j1], w11 = wf[1 * NE + j1], w12 = wf[2 * NE + j1];
        float w20 = 0.f, w21 = 0.f, w22 = 0.f;
        if (j2 < NROWS) {
            w20 = wf[0 * NE + j2]; w21 = wf[1 * NE + j2]; w22 = wf[2 * NE + j2];
        }
        const float* Kb1 = K + (size_t)row * NE + j1;
        const float* Kb2 = K + (size_t)row * NE + j2;
        float s0 = Kb1[0 * PL] * w10 + Kb1[1 * PL] * w11 + Kb1[2 * PL] * w12
                 + Kb2[0 * PL] * w20 + Kb2[1 * PL] * w21 + Kb2[2 * PL] * w22;
        float s1 = Kb1[3 * PL] * w10 + Kb1[4 * PL] * w11 + Kb1[5 * PL] * w12
                 + Kb2[3 * PL] * w20 + Kb2[4 * PL] * w21 + Kb2[5 * PL] * w22;
        float s2 = Kb1[6 * PL] * w10 + Kb1[7 * PL] * w11 + Kb1[8 * PL] * w12
                 + Kb2[6 * PL] * w20 + Kb2[7 * PL] * w21 + Kb2[8 * PL] * w22;
#pragma unroll
        for (int d = 32; d; d >>= 1) {
            s0 += __shfl_xor(s0, d);
            s1 += __shfl_xor(s1, d);
            s2 += __shfl_xor(s2, d);
        }
        if (lane == 0) {
            atomicAdd(&acc[0 * NE + row], s0);
            atomicAdd(&acc[1 * NE + row], s1);
            atomicAdd(&acc[2 * NE + row], s2);
        }
    }
    // barrier drains vmcnt(0) -> this WG's RMWs globally performed before ticket
    __syncthreads();
    if (tid == 0) {
        int ret = __hip_atomic_fetch_add(&cnt[m], 1, __ATOMIC_RELAXED,
                                         __HIP_MEMORY_SCOPE_AGENT);
        win = (ret == gridDim.x - 1) ? 1 : 0;
    }
    __syncthreads();
    if (!win) return;

    // ---- winner: chained pair apply ----
    __shared__ float aL[BR];        // a_C, then reused staging
    __shared__ float aL2[BR];       // a_A + z
    __shared__ float wyP[3][BS];    // w_j * F_C, species-major for phase B
    float dy = dy_of(E);
    int r = tid >> 1, h = tid & 1;  // 384 active threads: 2 per output row

    // phase A: load a_C
    if (tid < BR) {
        int jj = tid / 3, p = tid % 3;
        aL[tid] = __hip_atomic_load(&acc[p * NE + jC0 + jj], __ATOMIC_RELAXED,
                                    __HIP_MEMORY_SCOPE_AGENT);
    }
    __syncthreads();
    // F_C = G[C] @ a_C
    if (tid < 2 * BR) {
        const float4* grow = (const float4*)(G + ((size_t)C * BR + r) * BR) + h * 24;
        const float4* av = (const float4*)aL + h * 24;
        float s0 = 0.f, s1 = 0.f;
#pragma unroll
        for (int c = 0; c < 24; c += 2) {
            float4 g0 = grow[c], g1 = grow[c + 1];
            float4 a0 = av[c], a1 = av[c + 1];
            s0 += g0.x * a0.x + g0.y * a0.y + g0.z * a0.z + g0.w * a0.w;
            s1 += g1.x * a1.x + g1.y * a1.y + g1.z * a1.z + g1.w * a1.w;
        }
        float s = s0 + s1;
        s += __shfl_xor(s, 1);
        if (h == 0) {
            int jj = r / 3, x = r % 3;
            int j = jC0 + jj;
            float w = (j < NROWS) ? dy * E[j] : 0.f;
            if (j < NROWS) {
                out[(1 + x) * NE + j] = s > 0.f ? s : 0.f;
                wf[x * NE + j] = w * s;
            }
            wyP[x][jj] = w * s;
        }
    }
    __syncthreads();
    // phase B: z = Dnear @ F_C ; aL2 = a_A + z
    if (tid < 2 * BR) {
        int ii = r / 3, x = r % 3;
        int i = iA0 + ii;
        float s0 = 0.f, s1 = 0.f;
#pragma unroll
        for (int p = 0; p < 3; ++p) {
            const float4* kp = (const float4*)(K + (size_t)(x * 3 + p) * PL +
                                               (size_t)i * NE + jC0) + h * 8;
            const float4* wy = (const float4*)&wyP[p][0] + h * 8;
#pragma unroll
            for (int q = 0; q < 8; q += 2) {
                float4 k0 = kp[q], k1 = kp[q + 1];
                float4 y0 = wy[q], y1 = wy[q + 1];
                s0 += k0.x * y0.x + k0.y * y0.y + k0.z * y0.z + k0.w * y0.w;
                s1 += k1.x * y1.x + k1.y * y1.y + k1.z * y1.z + k1.w * y1.w;
            }
        }
        float z = s0 + s1;
        z += __shfl_xor(z, 1);
        if (h == 0) {
            aL2[r] = z + __hip_atomic_load(&acc[x * NE + i], __ATOMIC_RELAXED,
                                           __HIP_MEMORY_SCOPE_AGENT);
        }
    }
    __syncthreads();
    // phase C: F_A = G[A] @ aL2
    if (tid < 2 * BR) {
        const float4* grow = (const float4*)(G + ((size_t)A * BR + r) * BR) + h * 24;
        const float4* av = (const float4*)aL2 + h * 24;
        float s0 = 0.f, s1 = 0.f;
#pragma unroll
        for (int c = 0; c < 24; c += 2) {
            float4 g0 = grow[c], g1 = grow[c + 1];
            float4 a0 = av[c], a1 = av[c + 1];
            s0 += g0.x * a0.x + g0.y * a0.y + g0.z * a0.z + g0.w * a0.w;
            s1 += g1.x * a1.x + g1.y * a1.y + g1.z * a1.z + g1.w * a1.w;
        }
        float s = s0 + s1;
        s += __shfl_xor(s, 1);
        if (h == 0) {
            int ii = r / 3, x = r % 3;
            int i = iA0 + ii;
            out[(1 + x) * NE + i] = s > 0.f ? s : 0.f;
            wf[x * NE + i] = dy * E[i] * s;
        }
    }
}

extern "C" void kernel_launch(void* const* d_in, const int* in_sizes, int n_in,
                              void* d_out, int out_size, void* d_ws, size_t ws_size,
                              hipStream_t stream) {
    const float* E = (const float*)d_in[0];
    const float* R = (const float*)d_in[1];
    const float* K = (const float*)d_in[2];
    const float* S0 = (const float*)d_in[3];
    const float* SC = (const float*)d_in[4];
    float* out = (float*)d_out;
    float* wf = (float*)d_ws;
    float* acc = wf + NX * NE;
    float* G = acc + NX * NE;
    int* cnt = (int*)(G + (size_t)NBLK * BR * BR);

    k_init<<<(NE + 255) / 256, 256, 0, stream>>>(E, R, K, S0, SC, out, wf, acc, cnt);
    k_tinv<<<dim3(NBLK, 3), TTH, 0, stream>>>(E, R, K, G);

    for (int m = NPAIR - 1; m >= 0; --m) {
        int nFar = (m < NPAIR - 1) ? (2 * m + 2) * 8 : 0;
        k_pair<<<nFar + 1, 512, 0, stream>>>(E, K, G, acc, wf, out, cnt, m, nFar);
    }
}

// Round 10
// 377.079 us; speedup vs baseline: 1.1343x; 1.1343x over previous
//
#include <hip/hip_runtime.h>
#include <cstddef>
#include <cstdint>

#define NE 2048
#define NX 3
#define NROWS (NE - 1)               // rows solved by back-substitution: i = 0..2046
#define BS 64                        // block size (rows per block)
#define BR (3 * BS)                  // 192
#define NBLK 32
#define NPAIR 16
#define NCH 8                        // K-staging chunks in k_tinv
#define CHS 8                        // steps per chunk (NCH*CHS == BS)
#define CHQ (CHS * 9 * BS)           // 4608 floats per chunk
#define TTH 512                      // k_tinv threads
#define PERTH (CHQ / TTH)            // 9 floats per thread

// ws layout (floats):
//   wf  [3*NE]        @ 0          wf[p][j] = w_j * F[p][j]
//   acc [3*NE]        @ 3*NE       running RHS accumulator
//   G   [NBLK*BR*BR]  @ 6*NE       per-block T^{-1}, ROW-major: G[b][row][col]

static __device__ __forceinline__ float dy_of(const float* E) {
    return logf(E[NE - 1] / E[0]) / (float)(NE - 1);
}

__global__ void k_init(const float* __restrict__ E, const float* __restrict__ R,
                       const float* __restrict__ K, const float* __restrict__ S0,
                       const float* __restrict__ SC,
                       float* __restrict__ out, float* __restrict__ wf,
                       float* __restrict__ acc) {
    int i = blockIdx.x * blockDim.x + threadIdx.x;
    if (i >= NE) return;
    const size_t PL = (size_t)NE * NE;
    float dy = dy_of(E);
    float wlast = 0.5f * dy * E[NE - 1];
    float srcl[NX], Fl[NX];
#pragma unroll
    for (int p = 0; p < NX; ++p) srcl[p] = S0[p] / R[p * NE + NE - 1];
#pragma unroll
    for (int x = 0; x < NX; ++x) {
        float s = SC[x * NE + NE - 1];
#pragma unroll
        for (int p = 0; p < NX; ++p)
            s += K[(size_t)(x * NX + p) * PL + (size_t)(NE - 1) * NE + (NE - 1)] * srcl[p];
        Fl[x] = s / R[x * NE + NE - 1];
    }
    out[i] = E[i];  // output row 0 = E_grid
    if (i == NE - 1) {
#pragma unroll
        for (int x = 0; x < NX; ++x) {
            out[(1 + x) * NE + i] = Fl[x] > 0.f ? Fl[x] : 0.f;
            wf[x * NE + i] = wlast * Fl[x];
            acc[x * NE + i] = 0.f;
        }
        return;
    }
#pragma unroll
    for (int x = 0; x < NX; ++x) {
        float s = SC[x * NE + i];
#pragma unroll
        for (int p = 0; p < NX; ++p)
            s += K[(size_t)(x * NX + p) * PL + (size_t)i * NE + (NE - 1)] *
                 (wlast * Fl[p] + srcl[p]);
        acc[x * NE + i] = s;
    }
}

// Per-block inverse. grid (NBLK, 3), 512 threads: 64 columns/WG, 8 threads/col.
__global__ __launch_bounds__(TTH) void k_tinv(const float* __restrict__ E,
                                              const float* __restrict__ R,
                                              const float* __restrict__ K,
                                              float* __restrict__ G) {
    __shared__ float4 Xs4[BS][BS + 1];  // 66560 B: [jj][cloc] = (x0,x1,x2,_)
    __shared__ float Kst[CHS][BS][12];  // 24576 B: w-folded K rows, slot 4r+p
    __shared__ float Binv[BS][9];
    __shared__ float wloc[BS];
    const size_t PL = (size_t)NE * NE;
    int b = blockIdx.x;
    int g = blockIdx.y;                 // column group 0..2
    int i0 = b * BS;
    int tid = threadIdx.x;
    float dy = dy_of(E);

    if (tid < BS) {
        int j = i0 + tid;
        wloc[tid] = (j < NE - 1) ? dy * E[j] : 0.f;
        int ii = tid, i = i0 + ii;
        float b00, b01, b02, b10, b11, b12, b20, b21, b22;
        if (i < NROWS) {
            float h = -0.5f * dy * E[i];
            size_t d = (size_t)i * NE + i;
            b00 = h * K[0 * PL + d] + R[0 * NE + i];
            b01 = h * K[1 * PL + d];
            b02 = h * K[2 * PL + d];
            b10 = h * K[3 * PL + d];
            b11 = h * K[4 * PL + d] + R[1 * NE + i];
            b12 = h * K[5 * PL + d];
            b20 = h * K[6 * PL + d];
            b21 = h * K[7 * PL + d];
            b22 = h * K[8 * PL + d] + R[2 * NE + i];
        } else {
            b00 = 1.f; b01 = 0.f; b02 = 0.f;
            b10 = 0.f; b11 = 1.f; b12 = 0.f;
            b20 = 0.f; b21 = 0.f; b22 = 1.f;
        }
        float C00 = b11 * b22 - b12 * b21;
        float C01 = -(b10 * b22 - b12 * b20);
        float C02 = b10 * b21 - b11 * b20;
        float C10 = -(b01 * b22 - b02 * b21);
        float C11 = b00 * b22 - b02 * b20;
        float C12 = -(b00 * b21 - b01 * b20);
        float C20 = b01 * b12 - b02 * b11;
        float C21 = -(b00 * b12 - b02 * b10);
        float C22 = b00 * b11 - b01 * b10;
        float inv = 1.f / (b00 * C00 + b01 * C01 + b02 * C02);
        Binv[ii][0] = C00 * inv; Binv[ii][1] = C10 * inv; Binv[ii][2] = C20 * inv;
        Binv[ii][3] = C01 * inv; Binv[ii][4] = C11 * inv; Binv[ii][5] = C21 * inv;
        Binv[ii][6] = C02 * inv; Binv[ii][7] = C12 * inv; Binv[ii][8] = C22 * inv;
    }
    __syncthreads();

    float rg[PERTH];
#pragma unroll
    for (int k = 0; k < PERTH; ++k) {
        int q = tid + k * TTH;
        int s = q / (9 * BS);
        int pair = (q / BS) % 9;
        int jj = q & (BS - 1);
        int row = i0 + (BS - 1) - s;
        rg[k] = K[(size_t)pair * PL + (size_t)row * NE + (i0 + jj)];
    }

    int cloc = tid >> 3, sub = tid & 7;
    int colb = g * BS + cloc;

    for (int c = 0; c < NCH; ++c) {
        if (c > 0) __syncthreads();
#pragma unroll
        for (int k = 0; k < PERTH; ++k) {
            int q = tid + k * TTH;
            int s = q / (9 * BS);
            int pair = (q / BS) % 9;
            int jj = q & (BS - 1);
            Kst[s][jj][4 * (pair / 3) + (pair % 3)] = rg[k] * wloc[jj];
        }
        __syncthreads();
        if (c + 1 < NCH) {
#pragma unroll
            for (int k = 0; k < PERTH; ++k) {
                int q = tid + k * TTH;
                int s = q / (9 * BS);
                int pair = (q / BS) % 9;
                int jj = q & (BS - 1);
                int row = i0 + (BS - 1) - ((c + 1) * CHS + s);
                rg[k] = K[(size_t)pair * PL + (size_t)row * NE + (i0 + jj)];
            }
        }
        for (int s = 0; s < CHS; ++s) {
            int ii = (BS - 1) - (c * CHS + s);
            int i = i0 + ii;
            float v0 = 0.f, v1 = 0.f, v2 = 0.f;
            if (sub == 0) {
                v0 = (colb == 3 * ii + 0) ? 1.f : 0.f;
                v1 = (colb == 3 * ii + 1) ? 1.f : 0.f;
                v2 = (colb == 3 * ii + 2) ? 1.f : 0.f;
            }
            if (i < NROWS) {
                for (int jj = ii + 1 + sub; jj < BS; jj += 8) {
                    const float* kp = &Kst[s][jj][0];
                    float4 k0 = *(const float4*)(kp);
                    float4 k1 = *(const float4*)(kp + 4);
                    float4 k2 = *(const float4*)(kp + 8);
                    float4 xv = Xs4[jj][cloc];
                    v0 += k0.x * xv.x + k0.y * xv.y + k0.z * xv.z;
                    v1 += k1.x * xv.x + k1.y * xv.y + k1.z * xv.z;
                    v2 += k2.x * xv.x + k2.y * xv.y + k2.z * xv.z;
                }
            }
            v0 += __shfl_xor(v0, 1); v0 += __shfl_xor(v0, 2); v0 += __shfl_xor(v0, 4);
            v1 += __shfl_xor(v1, 1); v1 += __shfl_xor(v1, 2); v1 += __shfl_xor(v1, 4);
            v2 += __shfl_xor(v2, 1); v2 += __shfl_xor(v2, 2); v2 += __shfl_xor(v2, 4);
            if (sub == 0) {
                float f0, f1, f2;
                if (i < NROWS) {
                    const float* bv = Binv[ii];
                    f0 = bv[0] * v0 + bv[1] * v1 + bv[2] * v2;
                    f1 = bv[3] * v0 + bv[4] * v1 + bv[5] * v2;
                    f2 = bv[6] * v0 + bv[7] * v1 + bv[8] * v2;
                } else {
                    f0 = v0; f1 = v1; f2 = v2;  // identity row (pad)
                }
                Xs4[ii][cloc] = make_float4(f0, f1, f2, 0.f);
            }
            __builtin_amdgcn_wave_barrier();  // order LDS write->read across steps
        }
    }
    __syncthreads();
    // bulk Gt dump, ROW-major: G[b][r][g*64+cl]
    float* Gb = G + (size_t)b * BR * BR;
    for (int t = tid; t < BS * BR; t += TTH) {
        int r = t / BS, cl = t % BS;
        Gb[(size_t)r * BR + g * BS + cl] = ((const float*)&Xs4[r / 3][cl])[r % 3];
    }
}

// Pair stage S(m), blocks A=2m, C=2m+1 — NO intra-kernel dependencies:
//   winner (bid 0): F_C = G[C]@a_C; z = Knear@(w*F_C); F_A = G[A]@(a_A+z).
//     Inputs: acc rows of A,C (complete from PREVIOUS kernels' far, stream-
//     ordered) + its own F_C + direct K reads. Independent of this kernel's far.
//   far (bid>=1): cols of blocks 2m,2m+1 (wf written by winner? NO — by THIS
//     winner's blocks' wf is consumed by LATER kernels; this kernel's far uses
//     cols 2m+2,2m+3 whose wf came from the PREVIOUS kernel) -> rows < 2m*64.
__global__ __launch_bounds__(512) void k_pair(const float* __restrict__ E,
                                              const float* __restrict__ K,
                                              const float* __restrict__ G,
                                              float* __restrict__ acc,
                                              float* __restrict__ wf,
                                              float* __restrict__ out,
                                              int m, int nFar) {
    const size_t PL = (size_t)NE * NE;
    int A = 2 * m, C = 2 * m + 1;
    int iA0 = A * BS, jC0 = C * BS;
    int tid = threadIdx.x;
    int bid = blockIdx.x;
    int lane = tid & 63, wv = tid >> 6;

    if (bid > 0) {
        // far: 8 rows per WG (one per wave), 128 cols (blocks 2m+2, 2m+3)
        int jbase = (2 * m + 2) * BS;
        int row = (bid - 1) * 8 + wv;
        int j1 = jbase + lane, j2 = j1 + BS;
        float w10 = wf[0 * NE + j1], w11 = wf[1 * NE + j1], w12 = wf[2 * NE + j1];
        float w20 = 0.f, w21 = 0.f, w22 = 0.f;
        if (j2 < NROWS) {
            w20 = wf[0 * NE + j2]; w21 = wf[1 * NE + j2]; w22 = wf[2 * NE + j2];
        }
        const float* Kb1 = K + (size_t)row * NE + j1;
        const float* Kb2 = K + (size_t)row * NE + j2;
        float s0 = Kb1[0 * PL] * w10 + Kb1[1 * PL] * w11 + Kb1[2 * PL] * w12
                 + Kb2[0 * PL] * w20 + Kb2[1 * PL] * w21 + Kb2[2 * PL] * w22;
        float s1 = Kb1[3 * PL] * w10 + Kb1[4 * PL] * w11 + Kb1[5 * PL] * w12
                 + Kb2[3 * PL] * w20 + Kb2[4 * PL] * w21 + Kb2[5 * PL] * w22;
        float s2 = Kb1[6 * PL] * w10 + Kb1[7 * PL] * w11 + Kb1[8 * PL] * w12
                 + Kb2[6 * PL] * w20 + Kb2[7 * PL] * w21 + Kb2[8 * PL] * w22;
#pragma unroll
        for (int d = 32; d; d >>= 1) {
            s0 += __shfl_xor(s0, d);
            s1 += __shfl_xor(s1, d);
            s2 += __shfl_xor(s2, d);
        }
        if (lane == 0) {
            atomicAdd(&acc[0 * NE + row], s0);
            atomicAdd(&acc[1 * NE + row], s1);
            atomicAdd(&acc[2 * NE + row], s2);
        }
        return;
    }

    // ---- winner (bid 0): chained pair apply, starts immediately ----
    __shared__ float aL[BR];
    __shared__ float aL2[BR];
    __shared__ float wyP[3][BS];    // w_j * F_C, species-major for phase B
    float dy = dy_of(E);
    int r = tid >> 1, h = tid & 1;  // 384 active threads: 2 per output row

    // phase A: load a_C
    if (tid < BR) {
        int jj = tid / 3, p = tid % 3;
        aL[tid] = __hip_atomic_load(&acc[p * NE + jC0 + jj], __ATOMIC_RELAXED,
                                    __HIP_MEMORY_SCOPE_AGENT);
    }
    __syncthreads();
    // F_C = G[C] @ a_C
    if (tid < 2 * BR) {
        const float4* grow = (const float4*)(G + ((size_t)C * BR + r) * BR) + h * 24;
        const float4* av = (const float4*)aL + h * 24;
        float s0 = 0.f, s1 = 0.f;
#pragma unroll
        for (int c = 0; c < 24; c += 2) {
            float4 g0 = grow[c], g1 = grow[c + 1];
            float4 a0 = av[c], a1 = av[c + 1];
            s0 += g0.x * a0.x + g0.y * a0.y + g0.z * a0.z + g0.w * a0.w;
            s1 += g1.x * a1.x + g1.y * a1.y + g1.z * a1.z + g1.w * a1.w;
        }
        float s = s0 + s1;
        s += __shfl_xor(s, 1);
        if (h == 0) {
            int jj = r / 3, x = r % 3;
            int j = jC0 + jj;
            float w = (j < NROWS) ? dy * E[j] : 0.f;
            if (j < NROWS) {
                out[(1 + x) * NE + j] = s > 0.f ? s : 0.f;
                wf[x * NE + j] = w * s;
            }
            wyP[x][jj] = w * s;
        }
    }
    __syncthreads();
    // phase B: z = Dnear @ (w*F_C) ; aL2 = a_A + z
    if (tid < 2 * BR) {
        int ii = r / 3, x = r % 3;
        int i = iA0 + ii;
        float s0 = 0.f, s1 = 0.f;
#pragma unroll
        for (int p = 0; p < 3; ++p) {
            const float4* kp = (const float4*)(K + (size_t)(x * 3 + p) * PL +
                                               (size_t)i * NE + jC0) + h * 8;
            const float4* wy = (const float4*)&wyP[p][0] + h * 8;
#pragma unroll
            for (int q = 0; q < 8; q += 2) {
                float4 k0 = kp[q], k1 = kp[q + 1];
                float4 y0 = wy[q], y1 = wy[q + 1];
                s0 += k0.x * y0.x + k0.y * y0.y + k0.z * y0.z + k0.w * y0.w;
                s1 += k1.x * y1.x + k1.y * y1.y + k1.z * y1.z + k1.w * y1.w;
            }
        }
        float z = s0 + s1;
        z += __shfl_xor(z, 1);
        if (h == 0) {
            aL2[r] = z + __hip_atomic_load(&acc[x * NE + iA0 + ii], __ATOMIC_RELAXED,
                                           __HIP_MEMORY_SCOPE_AGENT);
        }
    }
    __syncthreads();
    // phase C: F_A = G[A] @ aL2
    if (tid < 2 * BR) {
        const float4* grow = (const float4*)(G + ((size_t)A * BR + r) * BR) + h * 24;
        const float4* av = (const float4*)aL2 + h * 24;
        float s0 = 0.f, s1 = 0.f;
#pragma unroll
        for (int c = 0; c < 24; c += 2) {
            float4 g0 = grow[c], g1 = grow[c + 1];
            float4 a0 = av[c], a1 = av[c + 1];
            s0 += g0.x * a0.x + g0.y * a0.y + g0.z * a0.z + g0.w * a0.w;
            s1 += g1.x * a1.x + g1.y * a1.y + g1.z * a1.z + g1.w * a1.w;
        }
        float s = s0 + s1;
        s += __shfl_xor(s, 1);
        if (h == 0) {
            int ii = r / 3, x = r % 3;
            int i = iA0 + ii;
            out[(1 + x) * NE + i] = s > 0.f ? s : 0.f;
            wf[x * NE + i] = dy * E[i] * s;
        }
    }
}

extern "C" void kernel_launch(void* const* d_in, const int* in_sizes, int n_in,
                              void* d_out, int out_size, void* d_ws, size_t ws_size,
                              hipStream_t stream) {
    const float* E = (const float*)d_in[0];
    const float* R = (const float*)d_in[1];
    const float* K = (const float*)d_in[2];
    const float* S0 = (const float*)d_in[3];
    const float* SC = (const float*)d_in[4];
    float* out = (float*)d_out;
    float* wf = (float*)d_ws;
    float* acc = wf + NX * NE;
    float* G = acc + NX * NE;

    k_init<<<(NE + 255) / 256, 256, 0, stream>>>(E, R, K, S0, SC, out, wf, acc);
    k_tinv<<<dim3(NBLK, 3), TTH, 0, stream>>>(E, R, K, G);

    for (int m = NPAIR - 1; m >= 0; --m) {
        int nFar = (m < NPAIR - 1) ? (2 * m) * 8 : 0;  // rows < 2m*64, 8 rows/WG
        k_pair<<<nFar + 1, 512, 0, stream>>>(E, K, G, acc, wf, out, m, nFar);
    }
}

// Round 11
// 303.983 us; speedup vs baseline: 1.4071x; 1.2405x over previous
//
#include <hip/hip_runtime.h>
#include <cstddef>
#include <cstdint>

#define NE 2048
#define NX 3
#define NROWS (NE - 1)               // rows solved: i = 0..2046
#define BS 64                        // block size (rows per block)
#define BR (3 * BS)                  // 192
#define NBLK 32
#define NPAIR 16
#define NCH 8                        // K-staging chunks in k_tinv
#define CHS 8                        // steps per chunk
#define CHQ (CHS * 9 * BS)           // 4608 floats per chunk
#define TTH 512                      // k_tinv threads
#define PERTH (CHQ / TTH)            // 9 floats per thread

// ws layout (floats):
//   wf   [3*NE]            @ 0
//   acc  [3*NE]            @ 3*NE
//   G    [32*BR*BR]        @ 6*NE            T^{-1} per block, row-major
//   ops1 [32][3][BR*BR]    @ after G         H (t=1), J2 (t=2), J3 (t=3)
//   pr   [16][3][BR*BR]    @ after ops1      P, R2, R3 per pair

static __device__ __forceinline__ float dy_of(const float* E) {
    return logf(E[NE - 1] / E[0]) / (float)(NE - 1);
}

__global__ void k_init(const float* __restrict__ E, const float* __restrict__ R,
                       const float* __restrict__ K, const float* __restrict__ S0,
                       const float* __restrict__ SC,
                       float* __restrict__ out, float* __restrict__ wf,
                       float* __restrict__ acc) {
    int i = blockIdx.x * blockDim.x + threadIdx.x;
    if (i >= NE) return;
    const size_t PL = (size_t)NE * NE;
    float dy = dy_of(E);
    float wlast = 0.5f * dy * E[NE - 1];
    float srcl[NX], Fl[NX];
#pragma unroll
    for (int p = 0; p < NX; ++p) srcl[p] = S0[p] / R[p * NE + NE - 1];
#pragma unroll
    for (int x = 0; x < NX; ++x) {
        float s = SC[x * NE + NE - 1];
#pragma unroll
        for (int p = 0; p < NX; ++p)
            s += K[(size_t)(x * NX + p) * PL + (size_t)(NE - 1) * NE + (NE - 1)] * srcl[p];
        Fl[x] = s / R[x * NE + NE - 1];
    }
    out[i] = E[i];
    if (i == NE - 1) {
#pragma unroll
        for (int x = 0; x < NX; ++x) {
            out[(1 + x) * NE + i] = Fl[x] > 0.f ? Fl[x] : 0.f;
            wf[x * NE + i] = wlast * Fl[x];
            acc[x * NE + i] = 0.f;
        }
        return;
    }
#pragma unroll
    for (int x = 0; x < NX; ++x) {
        float s = SC[x * NE + i];
#pragma unroll
        for (int p = 0; p < NX; ++p)
            s += K[(size_t)(x * NX + p) * PL + (size_t)i * NE + (NE - 1)] *
                 (wlast * Fl[p] + srcl[p]);
        acc[x * NE + i] = s;
    }
}

// Per-block inverse (R7-proven). grid (NBLK,3), 512 thr: 64 cols/WG, 8 thr/col.
__global__ __launch_bounds__(TTH) void k_tinv(const float* __restrict__ E,
                                              const float* __restrict__ R,
                                              const float* __restrict__ K,
                                              float* __restrict__ G) {
    __shared__ float4 Xs4[BS][BS + 1];
    __shared__ float Kst[CHS][BS][12];
    __shared__ float Binv[BS][9];
    __shared__ float wloc[BS];
    const size_t PL = (size_t)NE * NE;
    int b = blockIdx.x;
    int g = blockIdx.y;
    int i0 = b * BS;
    int tid = threadIdx.x;
    float dy = dy_of(E);

    if (tid < BS) {
        int j = i0 + tid;
        wloc[tid] = (j < NE - 1) ? dy * E[j] : 0.f;
        int ii = tid, i = i0 + ii;
        float b00, b01, b02, b10, b11, b12, b20, b21, b22;
        if (i < NROWS) {
            float h = -0.5f * dy * E[i];
            size_t d = (size_t)i * NE + i;
            b00 = h * K[0 * PL + d] + R[0 * NE + i];
            b01 = h * K[1 * PL + d];
            b02 = h * K[2 * PL + d];
            b10 = h * K[3 * PL + d];
            b11 = h * K[4 * PL + d] + R[1 * NE + i];
            b12 = h * K[5 * PL + d];
            b20 = h * K[6 * PL + d];
            b21 = h * K[7 * PL + d];
            b22 = h * K[8 * PL + d] + R[2 * NE + i];
        } else {
            b00 = 1.f; b01 = 0.f; b02 = 0.f;
            b10 = 0.f; b11 = 1.f; b12 = 0.f;
            b20 = 0.f; b21 = 0.f; b22 = 1.f;
        }
        float C00 = b11 * b22 - b12 * b21;
        float C01 = -(b10 * b22 - b12 * b20);
        float C02 = b10 * b21 - b11 * b20;
        float C10 = -(b01 * b22 - b02 * b21);
        float C11 = b00 * b22 - b02 * b20;
        float C12 = -(b00 * b21 - b01 * b20);
        float C20 = b01 * b12 - b02 * b11;
        float C21 = -(b00 * b12 - b02 * b10);
        float C22 = b00 * b11 - b01 * b10;
        float inv = 1.f / (b00 * C00 + b01 * C01 + b02 * C02);
        Binv[ii][0] = C00 * inv; Binv[ii][1] = C10 * inv; Binv[ii][2] = C20 * inv;
        Binv[ii][3] = C01 * inv; Binv[ii][4] = C11 * inv; Binv[ii][5] = C21 * inv;
        Binv[ii][6] = C02 * inv; Binv[ii][7] = C12 * inv; Binv[ii][8] = C22 * inv;
    }
    __syncthreads();

    float rg[PERTH];
#pragma unroll
    for (int k = 0; k < PERTH; ++k) {
        int q = tid + k * TTH;
        int s = q / (9 * BS);
        int pair = (q / BS) % 9;
        int jj = q & (BS - 1);
        int row = i0 + (BS - 1) - s;
        rg[k] = K[(size_t)pair * PL + (size_t)row * NE + (i0 + jj)];
    }

    int cloc = tid >> 3, sub = tid & 7;
    int colb = g * BS + cloc;

    for (int c = 0; c < NCH; ++c) {
        if (c > 0) __syncthreads();
#pragma unroll
        for (int k = 0; k < PERTH; ++k) {
            int q = tid + k * TTH;
            int s = q / (9 * BS);
            int pair = (q / BS) % 9;
            int jj = q & (BS - 1);
            Kst[s][jj][4 * (pair / 3) + (pair % 3)] = rg[k] * wloc[jj];
        }
        __syncthreads();
        if (c + 1 < NCH) {
#pragma unroll
            for (int k = 0; k < PERTH; ++k) {
                int q = tid + k * TTH;
                int s = q / (9 * BS);
                int pair = (q / BS) % 9;
                int jj = q & (BS - 1);
                int row = i0 + (BS - 1) - ((c + 1) * CHS + s);
                rg[k] = K[(size_t)pair * PL + (size_t)row * NE + (i0 + jj)];
            }
        }
        for (int s = 0; s < CHS; ++s) {
            int ii = (BS - 1) - (c * CHS + s);
            int i = i0 + ii;
            float v0 = 0.f, v1 = 0.f, v2 = 0.f;
            if (sub == 0) {
                v0 = (colb == 3 * ii + 0) ? 1.f : 0.f;
                v1 = (colb == 3 * ii + 1) ? 1.f : 0.f;
                v2 = (colb == 3 * ii + 2) ? 1.f : 0.f;
            }
            if (i < NROWS) {
                for (int jj = ii + 1 + sub; jj < BS; jj += 8) {
                    const float* kp = &Kst[s][jj][0];
                    float4 k0 = *(const float4*)(kp);
                    float4 k1 = *(const float4*)(kp + 4);
                    float4 k2 = *(const float4*)(kp + 8);
                    float4 xv = Xs4[jj][cloc];
                    v0 += k0.x * xv.x + k0.y * xv.y + k0.z * xv.z;
                    v1 += k1.x * xv.x + k1.y * xv.y + k1.z * xv.z;
                    v2 += k2.x * xv.x + k2.y * xv.y + k2.z * xv.z;
                }
            }
            v0 += __shfl_xor(v0, 1); v0 += __shfl_xor(v0, 2); v0 += __shfl_xor(v0, 4);
            v1 += __shfl_xor(v1, 1); v1 += __shfl_xor(v1, 2); v1 += __shfl_xor(v1, 4);
            v2 += __shfl_xor(v2, 1); v2 += __shfl_xor(v2, 2); v2 += __shfl_xor(v2, 4);
            if (sub == 0) {
                float f0, f1, f2;
                if (i < NROWS) {
                    const float* bv = Binv[ii];
                    f0 = bv[0] * v0 + bv[1] * v1 + bv[2] * v2;
                    f1 = bv[3] * v0 + bv[4] * v1 + bv[5] * v2;
                    f2 = bv[6] * v0 + bv[7] * v1 + bv[8] * v2;
                } else {
                    f0 = v0; f1 = v1; f2 = v2;
                }
                Xs4[ii][cloc] = make_float4(f0, f1, f2, 0.f);
            }
            __builtin_amdgcn_wave_barrier();
        }
    }
    __syncthreads();
    float* Gb = G + (size_t)b * BR * BR;
    for (int t = tid; t < BS * BR; t += TTH) {
        int r = t / BS, cl = t % BS;
        Gb[(size_t)r * BR + g * BS + cl] = ((const float*)&Xs4[r / 3][cl])[r % 3];
    }
}

// ops1[s][t-1] = G[s] @ Kp(s, s+t), t=1..3.  Kp[k=3ii+x][c=3jj+p] =
// K[x][p][s*64+ii][(s+t)*64+jj], zero where col >= NROWS. grid (32,3,3).
__global__ __launch_bounds__(256) void k_gops1(const float* __restrict__ K,
                                               const float* __restrict__ G,
                                               float* __restrict__ ops1) {
    int s = blockIdx.x, ty_ = blockIdx.y, rt = blockIdx.z;
    int t = ty_ + 1;
    float* O = ops1 + ((size_t)(s * 3 + ty_)) * BR * BR;
    int tid = threadIdx.x;
    if (s + t > NBLK - 1) {  // target block doesn't exist -> zero slab
        float* O2 = O + (size_t)rt * 64 * BR;
        for (int q = tid; q < 64 * BR; q += 256) O2[q] = 0.f;
        return;
    }
    __shared__ float As[64][193];
    __shared__ float Bs[BR][66];
    const size_t PL = (size_t)NE * NE;
    const float* Ga = G + (size_t)s * BR * BR + (size_t)rt * 64 * BR;
    for (int q = tid; q < 64 * BR; q += 256) {
        int r = q / BR, k = q % BR;
        As[r][k] = Ga[(size_t)r * BR + k];
    }
    int tgt0 = (s + t) * 64;
    for (int q = tid; q < BR * 64; q += 256) {
        int k = q / 64, c = q % 64;
        int ii = k / 3, x = k % 3, jj = c / 3, p = c % 3;
        int j = tgt0 + jj;
        Bs[k][c] = (j < NROWS)
            ? K[(size_t)(x * 3 + p) * PL + (size_t)(s * 64 + ii) * NE + j] : 0.f;
    }
    __syncthreads();
    int tx = tid & 15, ty = tid >> 4;
    // three column-chunks of 64 handled by... chunk = this WG covers cols [0,64)
    // per z? No: output is 64x192; loop chunks with Bs reloaded.
    for (int cc = 0; cc < 3; ++cc) {
        if (cc > 0) {
            __syncthreads();
            for (int q = tid; q < BR * 64; q += 256) {
                int k = q / 64, c = q % 64;
                int ii = k / 3, x = k % 3, jj = (cc * 64 + c) / 3, p = (cc * 64 + c) % 3;
                int j = tgt0 + jj;
                Bs[k][c] = (j < NROWS)
                    ? K[(size_t)(x * 3 + p) * PL + (size_t)(s * 64 + ii) * NE + j] : 0.f;
            }
            __syncthreads();
        }
        float av[4][4] = {};
        for (int k = 0; k < BR; ++k) {
            float b0 = Bs[k][tx * 4 + 0], b1 = Bs[k][tx * 4 + 1];
            float b2 = Bs[k][tx * 4 + 2], b3 = Bs[k][tx * 4 + 3];
#pragma unroll
            for (int i = 0; i < 4; ++i) {
                float a = As[ty * 4 + i][k];
                av[i][0] += a * b0; av[i][1] += a * b1;
                av[i][2] += a * b2; av[i][3] += a * b3;
            }
        }
#pragma unroll
        for (int i = 0; i < 4; ++i)
#pragma unroll
            for (int j = 0; j < 4; ++j)
                O[(size_t)(rt * 64 + ty * 4 + i) * BR + cc * 64 + tx * 4 + j] = av[i][j];
    }
}

// pr[m][w]: w=0: P = HwA@G_C; w=1: R2 = HwA@H_C + J2_A; w=2: R3 = HwA@J2_C + J3_A.
// HwA = H_A with col k scaled by w(C*64 + k/3). grid (16,3,3).
__global__ __launch_bounds__(256) void k_gops2(const float* __restrict__ E,
                                               const float* __restrict__ G,
                                               const float* __restrict__ ops1,
                                               float* __restrict__ pr) {
    int m = blockIdx.x, w = blockIdx.y, rt = blockIdx.z;
    int A = 2 * m, C = 2 * m + 1;
    int tid = threadIdx.x;
    __shared__ float As[64][193];
    __shared__ float Bs[BR][66];
    float dy = dy_of(E);
    const float* Asrc = ops1 + (size_t)(A * 3 + 0) * BR * BR + (size_t)rt * 64 * BR;
    const float* Bsrc = (w == 0) ? (G + (size_t)C * BR * BR)
                                 : (ops1 + (size_t)(C * 3 + (w - 1)) * BR * BR);
    const float* Dsrc = (w == 0) ? nullptr
                                 : (ops1 + (size_t)(A * 3 + w) * BR * BR);
    float* O = pr + (size_t)(m * 3 + w) * BR * BR;
    for (int q = tid; q < 64 * BR; q += 256) {
        int r = q / BR, k = q % BR;
        int j = C * 64 + k / 3;
        float wk = (j < NROWS) ? dy * E[j] : 0.f;
        As[r][k] = Asrc[(size_t)r * BR + k] * wk;
    }
    int tx = tid & 15, ty = tid >> 4;
    for (int cc = 0; cc < 3; ++cc) {
        __syncthreads();
        for (int q = tid; q < BR * 64; q += 256) {
            int k = q / 64, c = q % 64;
            Bs[k][c] = Bsrc[(size_t)k * BR + cc * 64 + c];
        }
        __syncthreads();
        float av[4][4] = {};
        for (int k = 0; k < BR; ++k) {
            float b0 = Bs[k][tx * 4 + 0], b1 = Bs[k][tx * 4 + 1];
            float b2 = Bs[k][tx * 4 + 2], b3 = Bs[k][tx * 4 + 3];
#pragma unroll
            for (int i = 0; i < 4; ++i) {
                float a = As[ty * 4 + i][k];
                av[i][0] += a * b0; av[i][1] += a * b1;
                av[i][2] += a * b2; av[i][3] += a * b3;
            }
        }
#pragma unroll
        for (int i = 0; i < 4; ++i)
#pragma unroll
            for (int j = 0; j < 4; ++j) {
                size_t o = (size_t)(rt * 64 + ty * 4 + i) * BR + cc * 64 + tx * 4 + j;
                float dv = Dsrc ? Dsrc[o] : 0.f;
                O[o] = av[i][j] + dv;
            }
    }
}

// Pair stage (no intra-kernel deps, no ticket):
//   bid 0..5 : F_C rows [bid*32,+32) = G_C aC + H_C v2 + J2_C v3
//   bid 6..11: F_A rows = G_A aA + P aC + R2 v2 + R3 v3
//   bid >=12 : far — cols blocks 2m+2,2m+3 -> rows < 2m*64
__global__ __launch_bounds__(512) void k_pair2(const float* __restrict__ E,
                                               const float* __restrict__ K,
                                               const float* __restrict__ G,
                                               const float* __restrict__ ops1,
                                               const float* __restrict__ pr,
                                               float* __restrict__ acc,
                                               float* __restrict__ wf,
                                               float* __restrict__ out,
                                               int m, int hasV) {
    const size_t PL = (size_t)NE * NE;
    int A = 2 * m, C = 2 * m + 1;
    int tid = threadIdx.x;
    int bid = blockIdx.x;
    int lane = tid & 63, wv = tid >> 6;

    if (bid >= 12) {
        int jbase = (2 * m + 2) * BS;
        int row = (bid - 12) * 8 + wv;
        int j1 = jbase + lane, j2 = j1 + BS;
        float w10 = wf[0 * NE + j1], w11 = wf[1 * NE + j1], w12 = wf[2 * NE + j1];
        float w20 = 0.f, w21 = 0.f, w22 = 0.f;
        if (j2 < NROWS) {
            w20 = wf[0 * NE + j2]; w21 = wf[1 * NE + j2]; w22 = wf[2 * NE + j2];
        }
        const float* Kb1 = K + (size_t)row * NE + j1;
        const float* Kb2 = K + (size_t)row * NE + j2;
        float s0 = Kb1[0 * PL] * w10 + Kb1[1 * PL] * w11 + Kb1[2 * PL] * w12
                 + Kb2[0 * PL] * w20 + Kb2[1 * PL] * w21 + Kb2[2 * PL] * w22;
        float s1 = Kb1[3 * PL] * w10 + Kb1[4 * PL] * w11 + Kb1[5 * PL] * w12
                 + Kb2[3 * PL] * w20 + Kb2[4 * PL] * w21 + Kb2[5 * PL] * w22;
        float s2 = Kb1[6 * PL] * w10 + Kb1[7 * PL] * w11 + Kb1[8 * PL] * w12
                 + Kb2[6 * PL] * w20 + Kb2[7 * PL] * w21 + Kb2[8 * PL] * w22;
#pragma unroll
        for (int d = 32; d; d >>= 1) {
            s0 += __shfl_xor(s0, d);
            s1 += __shfl_xor(s1, d);
            s2 += __shfl_xor(s2, d);
        }
        if (lane == 0) {
            atomicAdd(&acc[0 * NE + row], s0);
            atomicAdd(&acc[1 * NE + row], s1);
            atomicAdd(&acc[2 * NE + row], s2);
        }
        return;
    }

    // ---- apply ----
    __shared__ float4 vec4[4][BR / 4];        // aC, aA, v2, v3
    float dy = dy_of(E);
    if (tid < BR) {
        int jj = tid / 3, p = tid % 3;
        ((float*)vec4[0])[tid] = __hip_atomic_load(&acc[p * NE + C * BS + jj],
                                     __ATOMIC_RELAXED, __HIP_MEMORY_SCOPE_AGENT);
        ((float*)vec4[1])[tid] = __hip_atomic_load(&acc[p * NE + A * BS + jj],
                                     __ATOMIC_RELAXED, __HIP_MEMORY_SCOPE_AGENT);
        ((float*)vec4[2])[tid] = hasV ? wf[p * NE + (2 * m + 2) * BS + jj] : 0.f;
        ((float*)vec4[3])[tid] = hasV ? wf[p * NE + (2 * m + 3) * BS + jj] : 0.f;
    }
    __syncthreads();

    int rloc = tid >> 4, sub = tid & 15;      // 32 rows x 16 threads
    bool isC = (bid < 6);
    int rbase = (isC ? bid : bid - 6) * 32;
    int row = rbase + rloc;                   // layout row in [0,192)
    int blk = isC ? C : A;

    const float4* m0 = (const float4*)(G + ((size_t)blk * BR + row) * BR) + sub * 3;
    const float4 *m1, *m2, *m3 = nullptr;
    const float4 *x0, *x1, *x2, *x3 = nullptr;
    if (isC) {
        m1 = (const float4*)(ops1 + ((size_t)(C * 3 + 0) * BR + row) * BR) + sub * 3;
        m2 = (const float4*)(ops1 + ((size_t)(C * 3 + 1) * BR + row) * BR) + sub * 3;
        x0 = vec4[0] + sub * 3; x1 = vec4[2] + sub * 3; x2 = vec4[3] + sub * 3;
    } else {
        m1 = (const float4*)(pr + ((size_t)(m * 3 + 0) * BR + row) * BR) + sub * 3;
        m2 = (const float4*)(pr + ((size_t)(m * 3 + 1) * BR + row) * BR) + sub * 3;
        m3 = (const float4*)(pr + ((size_t)(m * 3 + 2) * BR + row) * BR) + sub * 3;
        x0 = vec4[1] + sub * 3; x1 = vec4[0] + sub * 3;
        x2 = vec4[2] + sub * 3; x3 = vec4[3] + sub * 3;
    }
    float s = 0.f;
#pragma unroll
    for (int q = 0; q < 3; ++q) {
        float4 g = m0[q], a = x0[q];
        s += g.x * a.x + g.y * a.y + g.z * a.z + g.w * a.w;
    }
    if (hasV || !isC) {
#pragma unroll
        for (int q = 0; q < 3; ++q) {
            float4 g = m1[q], a = x1[q];
            s += g.x * a.x + g.y * a.y + g.z * a.z + g.w * a.w;
        }
    }
    if (hasV) {
#pragma unroll
        for (int q = 0; q < 3; ++q) {
            float4 g = m2[q], a = x2[q];
            s += g.x * a.x + g.y * a.y + g.z * a.z + g.w * a.w;
        }
        if (!isC) {
#pragma unroll
            for (int q = 0; q < 3; ++q) {
                float4 g = m3[q], a = x3[q];
                s += g.x * a.x + g.y * a.y + g.z * a.z + g.w * a.w;
            }
        }
    }
    s += __shfl_xor(s, 1); s += __shfl_xor(s, 2);
    s += __shfl_xor(s, 4); s += __shfl_xor(s, 8);
    if (sub == 0) {
        int ii = row / 3, x = row % 3;
        int i = blk * BS + ii;
        if (i < NROWS) {
            out[(1 + x) * NE + i] = s > 0.f ? s : 0.f;
            wf[x * NE + i] = dy * E[i] * s;
        }
    }
}

extern "C" void kernel_launch(void* const* d_in, const int* in_sizes, int n_in,
                              void* d_out, int out_size, void* d_ws, size_t ws_size,
                              hipStream_t stream) {
    const float* E = (const float*)d_in[0];
    const float* R = (const float*)d_in[1];
    const float* K = (const float*)d_in[2];
    const float* S0 = (const float*)d_in[3];
    const float* SC = (const float*)d_in[4];
    float* out = (float*)d_out;
    float* wf = (float*)d_ws;
    float* acc = wf + NX * NE;
    float* G = acc + NX * NE;
    float* ops1 = G + (size_t)NBLK * BR * BR;
    float* pr = ops1 + (size_t)NBLK * 3 * BR * BR;

    k_init<<<(NE + 255) / 256, 256, 0, stream>>>(E, R, K, S0, SC, out, wf, acc);
    k_tinv<<<dim3(NBLK, 3), TTH, 0, stream>>>(E, R, K, G);
    k_gops1<<<dim3(NBLK, 3, 3), 256, 0, stream>>>(K, G, ops1);
    k_gops2<<<dim3(NPAIR, 3, 3), 256, 0, stream>>>(E, G, ops1, pr);

    for (int m = NPAIR - 1; m >= 0; --m) {
        int nFar = (m < NPAIR - 1) ? m * 16 : 0;
        int hasV = (m < NPAIR - 1) ? 1 : 0;
        k_pair2<<<12 + nFar, 512, 0, stream>>>(E, K, G, ops1, pr, acc, wf, out,
                                               m, hasV);
    }
}